// Round 2
// baseline (150.597 us; speedup 1.0000x reference)
//
#include <hip/hip_runtime.h>

// RAFT corr block: B=2, D=256, H=W=80, 4 levels, radius 4.
// avg_pool2(corr) over fmap2's spatial dims == corr with avg-pooled fmap2,
// so the 6400x6400 volume is never materialized.

typedef _Float16 h2 __attribute__((ext_vector_type(2)));

#define HWDIM 80
#define DCH 256

static __device__ __forceinline__ float dot2(h2 a, h2 b, float c) {
#if __has_builtin(__builtin_amdgcn_fdot2)
    return __builtin_amdgcn_fdot2(a, b, c, false);
#else
    return fmaf((float)a[0], (float)b[0], fmaf((float)a[1], (float)b[1], c));
#endif
}

// ---------------- transpose [B,256,6400] fp32 -> [B,6400,256] f16 ----------------
__global__ __launch_bounds__(256) void transpose_f16(const float* __restrict__ src,
                                                     _Float16* __restrict__ dst) {
    __shared__ float tile[256][33];
    int bid = blockIdx.x;
    int b = bid / 200;               // 6400/32 = 200 tiles per batch
    int s0 = (bid % 200) * 32;
    int t = threadIdx.x;
    const float* sb = src + (size_t)b * DCH * (HWDIM * HWDIM);
#pragma unroll 4
    for (int k = 0; k < 32; ++k) {
        int j = t + 256 * k;
        int c = j >> 5, s = j & 31;
        tile[c][s] = sb[(size_t)c * (HWDIM * HWDIM) + s0 + s];
    }
    __syncthreads();
    _Float16* db = dst + ((size_t)b * (HWDIM * HWDIM) + s0) * DCH;
    int p = t & 127;
    int srow = t >> 7;
#pragma unroll 4
    for (int k = 0; k < 16; ++k) {
        int s = 2 * k + srow;
        h2 v;
        v[0] = (_Float16)tile[2 * p][s];
        v[1] = (_Float16)tile[2 * p + 1][s];
        *(h2*)(db + (size_t)s * DCH + 2 * p) = v;
    }
}

// ---------------- 2x2 avg pool on [B,H,W,256] f16 ----------------
__global__ __launch_bounds__(256) void pool2(const _Float16* __restrict__ src,
                                             _Float16* __restrict__ dst,
                                             int Hl, int Wl, int total) {
    int i = blockIdx.x * 256 + threadIdx.x;
    if (i >= total) return;                 // total = B*Hl*Wl*128 (h2 units)
    int c2 = i & 127;
    int xy = i >> 7;
    int x = xy % Wl;
    int y = (xy / Wl) % Hl;
    int b = xy / (Wl * Hl);
    int Ws = Wl * 2;
    const h2* s = (const h2*)src + (((size_t)(b * (2 * Hl) + 2 * y) * Ws) + 2 * x) * 128 + c2;
    h2 v00 = s[0];
    h2 v01 = s[128];
    h2 v10 = s[(size_t)Ws * 128];
    h2 v11 = s[(size_t)Ws * 128 + 128];
    float r0 = ((float)v00[0] + (float)v01[0] + (float)v10[0] + (float)v11[0]) * 0.25f;
    float r1 = ((float)v00[1] + (float)v01[1] + (float)v10[1] + (float)v11[1]) * 0.25f;
    h2 o;
    o[0] = (_Float16)r0;
    o[1] = (_Float16)r1;
    ((h2*)dst)[i] = o;
}

// ---------------- main: 16 pixels (one row segment) per block ----------------
// 512 threads = 8 waves; wave w handles level (w&3), pixel half (w>>2).
// Within a wave: 4 taps in flight (g = lane>>4), 16 lanes/tap, 16 ch/lane (32B).
__global__ __launch_bounds__(512) void corr_sample16(
    const _Float16* __restrict__ f1h,
    const _Float16* __restrict__ f20, const _Float16* __restrict__ f21,
    const _Float16* __restrict__ f22, const _Float16* __restrict__ f23,
    const float* __restrict__ coords, float* __restrict__ out) {
    __shared__ float taps[4][16][101];     // padded: epilogue x-stride 101 -> conflict-free
    __shared__ float fxy[4][16][2];

    int n0 = blockIdx.x * 16;              // 16 consecutive pixels, same row
    int b = n0 / 6400;
    int y0 = (n0 / 80) % 80;
    int xb = n0 % 80;                      // multiple of 16
    int tid = threadIdx.x;
    int wave = tid >> 6;
    int L = wave & 3;
    int half = wave >> 2;
    int lane = tid & 63;
    int g = lane >> 4;                     // tap slot within group of 4
    int q = lane & 15;                     // channel chunk

    int Wl = HWDIM >> L;
    const h2* f2 = (const h2*)((L == 0 ? f20 : L == 1 ? f21 : L == 2 ? f22 : f23))
                   + (size_t)b * Wl * Wl * 128;
    float ls = 1.0f / (float)(1 << L);

    for (int p8 = 0; p8 < 8; ++p8) {
        int p = half * 8 + p8;
        int n = n0 + p;
        int x0 = xb + p;
        float cx = coords[((size_t)b * 2 + 0) * 6400 + y0 * 80 + x0];
        float cy = coords[((size_t)b * 2 + 1) * 6400 + y0 * 80 + x0];
        float cxl = cx * ls, cyl = cy * ls;
        float fxf = floorf(cxl), fyf = floorf(cyl);
        int X0 = (int)fxf - 4, Y0 = (int)fyf - 4;
        if (lane == 0) {
            fxy[L][p][0] = cxl - fxf;
            fxy[L][p][1] = cyl - fyf;
        }
        // f1 fragment: channels [16q,16q+16) split as [8q..] and [128+8q..]
        const float4* f1p = (const float4*)(f1h + (size_t)n * DCH);
        float4 fa = f1p[q], fb = f1p[q + 16];
        const h2* f1a = (const h2*)&fa;
        const h2* f1b = (const h2*)&fb;

        for (int grp = 0; grp < 25; ++grp) {
            int t = grp * 4 + g;           // tap 0..99
            int tx = t % 10, ty = t / 10;
            int xi = X0 + tx, yi = Y0 + ty;
            float acc = 0.f;
            if ((unsigned)xi < (unsigned)Wl && (unsigned)yi < (unsigned)Wl) {
                const float4* rp = (const float4*)(f2 + ((size_t)yi * Wl + xi) * 128);
                float4 ra = rp[q], rb = rp[q + 16];
                const h2* r2a = (const h2*)&ra;
                const h2* r2b = (const h2*)&rb;
#pragma unroll
                for (int u = 0; u < 4; ++u) {
                    acc = dot2(r2a[u], f1a[u], acc);
                    acc = dot2(r2b[u], f1b[u], acc);
                }
            }
            // reduce 16 sublanes (xor stays within 16-lane group)
            acc += __shfl_xor(acc, 1);
            acc += __shfl_xor(acc, 2);
            acc += __shfl_xor(acc, 4);
            acc += __shfl_xor(acc, 8);
            if (q == 0) taps[L][p][t] = acc * 0.0625f;   // / sqrt(256)
        }
    }
    __syncthreads();

    // epilogue: 4 levels x 81 k x 16 px = 5184 values; 16 consecutive lanes
    // share k -> 64B contiguous stores.
    for (int idx = tid; idx < 5184; idx += 512) {
        int Le = idx / 1296;
        int r = idx - Le * 1296;
        int k = r >> 4;
        int x = r & 15;
        int a = k / 9;                     // x-offset index
        int c = k - a * 9;                 // y-offset index
        float fx = fxy[Le][x][0], fy = fxy[Le][x][1];
        float t00 = taps[Le][x][c * 10 + a];
        float t01 = taps[Le][x][c * 10 + a + 1];
        float t10 = taps[Le][x][(c + 1) * 10 + a];
        float t11 = taps[Le][x][(c + 1) * 10 + a + 1];
        float v = (1.f - fy) * ((1.f - fx) * t00 + fx * t01)
                + fy * ((1.f - fx) * t10 + fx * t11);
        out[((size_t)b * 324 + Le * 81 + k) * 6400 + (size_t)y0 * 80 + xb + x] = v;
    }
}

extern "C" void kernel_launch(void* const* d_in, const int* in_sizes, int n_in,
                              void* d_out, int out_size, void* d_ws, size_t ws_size,
                              hipStream_t stream) {
    const float* fmap1 = (const float*)d_in[0];
    const float* fmap2 = (const float*)d_in[1];
    const float* coords = (const float*)d_in[2];
    float* out = (float*)d_out;
    char* ws = (char*)d_ws;

    _Float16* f1h = (_Float16*)(ws);                  // 2*6400*256*2 = 6553600 B
    _Float16* f20 = (_Float16*)(ws + 6553600);        // 6553600 B
    _Float16* f21 = (_Float16*)(ws + 13107200);       // 1638400 B
    _Float16* f22 = (_Float16*)(ws + 14745600);       // 409600 B
    _Float16* f23 = (_Float16*)(ws + 15155200);       // 102400 B

    transpose_f16<<<dim3(400), dim3(256), 0, stream>>>(fmap1, f1h);
    transpose_f16<<<dim3(400), dim3(256), 0, stream>>>(fmap2, f20);
    pool2<<<dim3(1600), dim3(256), 0, stream>>>(f20, f21, 40, 40, 2 * 40 * 40 * 128);
    pool2<<<dim3(400), dim3(256), 0, stream>>>(f21, f22, 20, 20, 2 * 20 * 20 * 128);
    pool2<<<dim3(100), dim3(256), 0, stream>>>(f22, f23, 10, 10, 2 * 10 * 10 * 128);
    corr_sample16<<<dim3(800), dim3(512), 0, stream>>>(f1h, f20, f21, f22, f23, coords, out);
}

// Round 3
// 149.153 us; speedup vs baseline: 1.0097x; 1.0097x over previous
//
#include <hip/hip_runtime.h>

// RAFT corr block: B=2, D=256, H=W=80, 4 levels, radius 4.
// avg_pool2(corr) over fmap2's spatial dims == corr with avg-pooled fmap2,
// so the 6400x6400 volume is never materialized.

typedef _Float16 h2 __attribute__((ext_vector_type(2)));

#define HWDIM 80
#define DCH 256

static __device__ __forceinline__ float dot2(h2 a, h2 b, float c) {
#if __has_builtin(__builtin_amdgcn_fdot2)
    return __builtin_amdgcn_fdot2(a, b, c, false);
#else
    return fmaf((float)a[0], (float)b[0], fmaf((float)a[1], (float)b[1], c));
#endif
}

// ---------------- transpose [B,256,6400] fp32 -> [B,6400,256] f16 ----------------
__global__ __launch_bounds__(256) void transpose_f16(const float* __restrict__ src,
                                                     _Float16* __restrict__ dst) {
    __shared__ float tile[256][33];
    int bid = blockIdx.x;
    int b = bid / 200;               // 6400/32 = 200 tiles per batch
    int s0 = (bid % 200) * 32;
    int t = threadIdx.x;
    const float* sb = src + (size_t)b * DCH * (HWDIM * HWDIM);
#pragma unroll 4
    for (int k = 0; k < 32; ++k) {
        int j = t + 256 * k;
        int c = j >> 5, s = j & 31;
        tile[c][s] = sb[(size_t)c * (HWDIM * HWDIM) + s0 + s];
    }
    __syncthreads();
    _Float16* db = dst + ((size_t)b * (HWDIM * HWDIM) + s0) * DCH;
    int p = t & 127;
    int srow = t >> 7;
#pragma unroll 4
    for (int k = 0; k < 16; ++k) {
        int s = 2 * k + srow;
        h2 v;
        v[0] = (_Float16)tile[2 * p][s];
        v[1] = (_Float16)tile[2 * p + 1][s];
        *(h2*)(db + (size_t)s * DCH + 2 * p) = v;
    }
}

// ---------------- 2x2 avg pool on [B,H,W,256] f16 ----------------
__global__ __launch_bounds__(256) void pool2(const _Float16* __restrict__ src,
                                             _Float16* __restrict__ dst,
                                             int Hl, int Wl, int total) {
    int i = blockIdx.x * 256 + threadIdx.x;
    if (i >= total) return;                 // total = B*Hl*Wl*128 (h2 units)
    int c2 = i & 127;
    int xy = i >> 7;
    int x = xy % Wl;
    int y = (xy / Wl) % Hl;
    int b = xy / (Wl * Hl);
    int Ws = Wl * 2;
    const h2* s = (const h2*)src + (((size_t)(b * (2 * Hl) + 2 * y) * Ws) + 2 * x) * 128 + c2;
    h2 v00 = s[0];
    h2 v01 = s[128];
    h2 v10 = s[(size_t)Ws * 128];
    h2 v11 = s[(size_t)Ws * 128 + 128];
    float r0 = ((float)v00[0] + (float)v01[0] + (float)v10[0] + (float)v11[0]) * 0.25f;
    float r1 = ((float)v00[1] + (float)v01[1] + (float)v10[1] + (float)v11[1]) * 0.25f;
    h2 o;
    o[0] = (_Float16)r0;
    o[1] = (_Float16)r1;
    ((h2*)dst)[i] = o;
}

// ---------------- main: 16 pixels (one row segment) per block ----------------
// 512 threads = 8 waves; 64 (px,level) tasks remixed across waves so every wave
// touches all 4 levels (load balance). Per task: 8 taps in flight (g = lane>>3),
// 8 lanes/tap, 32 ch/lane, software-pipelined group loop with clamped loads.
__global__ __launch_bounds__(512) void corr_sample16(
    const _Float16* __restrict__ f1h,
    const _Float16* __restrict__ f20, const _Float16* __restrict__ f21,
    const _Float16* __restrict__ f22, const _Float16* __restrict__ f23,
    const float* __restrict__ coords, float* __restrict__ out) {
    __shared__ float taps[4][16][105];     // stride 105 (odd): conflict-free epilogue
    __shared__ float fxy[4][16][2];

    int n0 = blockIdx.x * 16;              // 16 consecutive pixels, same row
    int b = n0 / 6400;
    int y0 = (n0 / 80) % 80;
    int xb = n0 % 80;                      // multiple of 16
    int tid = threadIdx.x;
    int w = tid >> 6;
    int lane = tid & 63;
    int g = lane >> 3;                     // tap slot 0..7
    int q = lane & 7;                      // channel chunk 0..7 (32 ch each)

    for (int i = 0; i < 8; ++i) {
        int j = w * 8 + i;
        int px = j & 15;
        int L = ((j >> 4) + px) & 3;       // each (px,L) covered exactly once
        int Wl = HWDIM >> L;
        const _Float16* f2 = (L == 0 ? f20 : L == 1 ? f21 : L == 2 ? f22 : f23)
                             + (size_t)b * Wl * Wl * DCH;
        float ls = 1.0f / (float)(1 << L);
        int x0 = xb + px;
        float cx = coords[((size_t)b * 2 + 0) * 6400 + y0 * 80 + x0];
        float cy = coords[((size_t)b * 2 + 1) * 6400 + y0 * 80 + x0];
        float cxl = cx * ls, cyl = cy * ls;
        float fxf = floorf(cxl), fyf = floorf(cyl);
        int X0 = (int)fxf - 4, Y0 = (int)fyf - 4;
        if (lane == 0) {
            fxy[L][px][0] = cxl - fxf;
            fxy[L][px][1] = cyl - fyf;
        }

        // f1 fragment: lane q covers channel chunks q*16B + u*128B (matches f2 pattern)
        const float4* f1p = (const float4*)(f1h + ((size_t)n0 + px) * DCH);
        float4 f1r[4];
#pragma unroll
        for (int u = 0; u < 4; ++u) f1r[u] = f1p[q + 8 * u];

        // software-pipelined tap-group loop: 13 groups x 8 taps (t<100 masked)
        int t0 = g;
        int ty0 = t0 / 10, tx0 = t0 - ty0 * 10;
        int xi = X0 + tx0, yi = Y0 + ty0;
        bool vcur = ((unsigned)xi < (unsigned)Wl) & ((unsigned)yi < (unsigned)Wl);
        {
        }
        const float4* pc = (const float4*)(f2 + ((size_t)min(max(yi, 0), Wl - 1) * Wl
                                                 + min(max(xi, 0), Wl - 1)) * DCH);
        float4 rc0 = pc[q], rc1 = pc[q + 8], rc2 = pc[q + 16], rc3 = pc[q + 24];

        for (int grp = 0; grp < 13; ++grp) {
            bool vnext = false;
            float4 rn0, rn1, rn2, rn3;
            if (grp < 12) {
                int t = (grp + 1) * 8 + g;
                int ty = t / 10, tx = t - ty * 10;
                int xn = X0 + tx, yn = Y0 + ty;
                vnext = ((unsigned)xn < (unsigned)Wl) & ((unsigned)yn < (unsigned)Wl)
                        & (t < 100);
                const float4* pn = (const float4*)(f2 + ((size_t)min(max(yn, 0), Wl - 1) * Wl
                                                         + min(max(xn, 0), Wl - 1)) * DCH);
                rn0 = pn[q]; rn1 = pn[q + 8]; rn2 = pn[q + 16]; rn3 = pn[q + 24];
            }
            float a0 = 0.f, a1 = 0.f, a2 = 0.f, a3 = 0.f;
            {
                const h2* r0 = (const h2*)&rc0; const h2* e0 = (const h2*)&f1r[0];
                const h2* r1 = (const h2*)&rc1; const h2* e1 = (const h2*)&f1r[1];
                const h2* r2 = (const h2*)&rc2; const h2* e2 = (const h2*)&f1r[2];
                const h2* r3 = (const h2*)&rc3; const h2* e3 = (const h2*)&f1r[3];
#pragma unroll
                for (int u = 0; u < 4; ++u) {
                    a0 = dot2(r0[u], e0[u], a0);
                    a1 = dot2(r1[u], e1[u], a1);
                    a2 = dot2(r2[u], e2[u], a2);
                    a3 = dot2(r3[u], e3[u], a3);
                }
            }
            float acc = (a0 + a1) + (a2 + a3);
            acc = vcur ? acc : 0.f;
            acc += __shfl_xor(acc, 1);
            acc += __shfl_xor(acc, 2);
            acc += __shfl_xor(acc, 4);
            int t = grp * 8 + g;
            if (q == 0 && t < 100) taps[L][px][t] = acc * 0.0625f;  // / sqrt(256)
            vcur = vnext;
            rc0 = rn0; rc1 = rn1; rc2 = rn2; rc3 = rn3;
        }
    }
    __syncthreads();

    // epilogue: 4 levels x 81 k x 16 px; 16 consecutive lanes share k -> 64B stores.
    for (int idx = tid; idx < 5184; idx += 512) {
        int Le = idx / 1296;
        int r = idx - Le * 1296;
        int k = r >> 4;
        int x = r & 15;
        int a = k / 9;                     // x-offset index
        int c = k - a * 9;                 // y-offset index
        float fx = fxy[Le][x][0], fy = fxy[Le][x][1];
        float t00 = taps[Le][x][c * 10 + a];
        float t01 = taps[Le][x][c * 10 + a + 1];
        float t10 = taps[Le][x][(c + 1) * 10 + a];
        float t11 = taps[Le][x][(c + 1) * 10 + a + 1];
        float v = (1.f - fy) * ((1.f - fx) * t00 + fx * t01)
                + fy * ((1.f - fx) * t10 + fx * t11);
        out[((size_t)b * 324 + Le * 81 + k) * 6400 + (size_t)y0 * 80 + xb + x] = v;
    }
}

extern "C" void kernel_launch(void* const* d_in, const int* in_sizes, int n_in,
                              void* d_out, int out_size, void* d_ws, size_t ws_size,
                              hipStream_t stream) {
    const float* fmap1 = (const float*)d_in[0];
    const float* fmap2 = (const float*)d_in[1];
    const float* coords = (const float*)d_in[2];
    float* out = (float*)d_out;
    char* ws = (char*)d_ws;

    _Float16* f1h = (_Float16*)(ws);                  // 2*6400*256*2 = 6553600 B
    _Float16* f20 = (_Float16*)(ws + 6553600);        // 6553600 B
    _Float16* f21 = (_Float16*)(ws + 13107200);       // 1638400 B
    _Float16* f22 = (_Float16*)(ws + 14745600);       // 409600 B
    _Float16* f23 = (_Float16*)(ws + 15155200);       // 102400 B

    transpose_f16<<<dim3(400), dim3(256), 0, stream>>>(fmap1, f1h);
    transpose_f16<<<dim3(400), dim3(256), 0, stream>>>(fmap2, f20);
    pool2<<<dim3(1600), dim3(256), 0, stream>>>(f20, f21, 40, 40, 2 * 40 * 40 * 128);
    pool2<<<dim3(400), dim3(256), 0, stream>>>(f21, f22, 20, 20, 2 * 20 * 20 * 128);
    pool2<<<dim3(100), dim3(256), 0, stream>>>(f22, f23, 10, 10, 2 * 10 * 10 * 128);
    corr_sample16<<<dim3(800), dim3(512), 0, stream>>>(f1h, f20, f21, f22, f23, coords, out);
}